// Round 1
// baseline (266.979 us; speedup 1.0000x reference)
//
#include <hip/hip_runtime.h>
#include <math.h>

// ---- problem constants ----
#define NCLS 80
#define NANC 3
#define NT   512
#define BSZ  16
#define MM   (NANC*NT)    // 1536
#define M5   (5*MM)       // 7680
#define EPSF 1e-7f

// level cell counts: bs*NA*H*W
#define C0 (16*3*80*80)   // 307200
#define C1 (16*3*40*40)   // 76800
#define C2 (16*3*20*20)   // 19200
#define CTOT (C0+C1+C2)   // 403200

__device__ __forceinline__ float bce_logit(float x, float y) {
    return fmaxf(x, 0.0f) - x * y + log1pf(expf(-fabsf(x)));
}
__device__ __forceinline__ float sigmoidf(float x) {
    return 1.0f / (1.0f + expf(-x));
}
__device__ __forceinline__ float wave_reduce(float v) {
    #pragma unroll
    for (int o = 32; o > 0; o >>= 1) v += __shfl_down(v, o);
    return v;
}
__device__ __forceinline__ int wave_reduce_i(int v) {
    #pragma unroll
    for (int o = 32; o > 0; o >>= 1) v += __shfl_down(v, o);
    return v;
}

// ws layout: acc[0..2]=sum_lbox per level, acc[3..5]=sum_lcls per level,
// acc[6]=lobj (pre-scaled mean contributions). nv[0..2] at +64B.
// tobj packed buffers at +128B: level0 [0,C0), level1 [C0,C0+C1), level2 [...).

// Kernel 1: per-candidate (5 offsets x NA x NT per level).
__global__ void cand_kernel(const float* __restrict__ p0,
                            const float* __restrict__ p1,
                            const float* __restrict__ p2,
                            const float* __restrict__ targets,
                            const float* __restrict__ anchors,
                            double* __restrict__ acc,
                            int* __restrict__ nv,
                            unsigned long long* __restrict__ tobj_base)
{
    const int level = blockIdx.y;
    const int r = blockIdx.x * blockDim.x + threadIdx.x;   // 0..M5-1

    const float* p; int W, H; unsigned long long* tobj;
    if (level == 0)      { p = p0; W = 80; H = 80; tobj = tobj_base; }
    else if (level == 1) { p = p1; W = 40; H = 40; tobj = tobj_base + C0; }
    else                 { p = p2; W = 20; H = 20; tobj = tobj_base + C0 + C1; }

    float lb = 0.0f, lc = 0.0f;
    int cnt = 0;

    if (r < M5) {
        const int off_idx = r / MM;
        const int m  = r - off_idx * MM;
        const int a  = m / NT;
        const int ti = m - a * NT;

        const float img = targets[ti*6 + 0];
        const float cls = targets[ti*6 + 1];
        const float gx  = targets[ti*6 + 2] * (float)W;
        const float gy  = targets[ti*6 + 3] * (float)H;
        const float gw  = targets[ti*6 + 4] * (float)W;
        const float gh  = targets[ti*6 + 5] * (float)H;

        const float aw = anchors[level*6 + a*2 + 0];
        const float ah = anchors[level*6 + a*2 + 1];

        // anchor ratio filter
        const float rw = gw / aw, rh = gh / ah;
        const float mr = fmaxf(fmaxf(rw, 1.0f/rw), fmaxf(rh, 1.0f/rh));
        const bool m0 = mr < 4.0f;

        // offset selection (YOLOv5 build_targets)
        const float fx  = gx - truncf(gx);
        const float fy  = gy - truncf(gy);
        const float gix = (float)W - gx;
        const float giy = (float)H - gy;
        const float fix_ = gix - truncf(gix);
        const float fiy  = giy - truncf(giy);

        bool sel; float ox = 0.0f, oy = 0.0f;
        switch (off_idx) {
            case 0: sel = true; break;
            case 1: sel = (fx   < 0.5f) && (gx  > 1.0f); ox =  0.5f; break;
            case 2: sel = (fy   < 0.5f) && (gy  > 1.0f); oy =  0.5f; break;
            case 3: sel = (fix_ < 0.5f) && (gix > 1.0f); ox = -0.5f; break;
            default:sel = (fiy  < 0.5f) && (giy > 1.0f); oy = -0.5f; break;
        }

        if (sel && m0) {
            const int b = (int)img;
            const int c = (int)cls;
            int gi = (int)truncf(gx - ox);
            int gj = (int)truncf(gy - oy);
            gi = min(max(gi, 0), W - 1);
            gj = min(max(gj, 0), H - 1);

            const float tbx = gx - (float)gi;
            const float tby = gy - (float)gj;

            const int cell = ((b*NANC + a)*H + gj)*W + gi;
            const float* ps = p + (size_t)cell * 85;

            const float s0 = ps[0], s1 = ps[1], s2 = ps[2], s3 = ps[3];
            const float pxc = sigmoidf(s0)*2.0f - 0.5f;
            const float pyc = sigmoidf(s1)*2.0f - 0.5f;
            float t2 = sigmoidf(s2)*2.0f; const float pw = t2*t2*aw;
            float t3 = sigmoidf(s3)*2.0f; const float ph = t3*t3*ah;

            // CIoU (exact EPS placement per reference)
            const float b1x1 = pxc - pw*0.5f, b1x2 = pxc + pw*0.5f;
            const float b1y1 = pyc - ph*0.5f, b1y2 = pyc + ph*0.5f;
            const float b2x1 = tbx - gw*0.5f, b2x2 = tbx + gw*0.5f;
            const float b2y1 = tby - gh*0.5f, b2y2 = tby + gh*0.5f;

            const float iw = fmaxf(fminf(b1x2, b2x2) - fmaxf(b1x1, b2x1), 0.0f);
            const float ih = fmaxf(fminf(b1y2, b2y2) - fmaxf(b1y1, b2y1), 0.0f);
            const float inter = iw * ih;

            const float w1 = b1x2 - b1x1, h1 = b1y2 - b1y1 + EPSF;
            const float w2 = b2x2 - b2x1, h2 = b2y2 - b2y1 + EPSF;
            const float uni = w1*h1 + w2*h2 - inter + EPSF;
            const float iou = inter / uni;

            const float cw = fmaxf(b1x2, b2x2) - fminf(b1x1, b2x1);
            const float chh = fmaxf(b1y2, b2y2) - fminf(b1y1, b2y1);
            const float c2 = cw*cw + chh*chh + EPSF;
            const float dx = b2x1 + b2x2 - b1x1 - b1x2;
            const float dy = b2y1 + b2y2 - b1y1 - b1y2;
            const float rho2 = (dx*dx + dy*dy) * 0.25f;

            const float dat = atanf(w2/h2) - atanf(w1/h1);
            const float v = (4.0f / (float)(M_PI*M_PI)) * dat * dat;
            const float alpha = v / (v - iou + (1.0f + EPSF));
            const float ciou = iou - (rho2/c2 + v*alpha);

            lb = 1.0f - ciou;
            cnt = 1;

            // obj_val = 1-GR + GR*clip(ciou,0) = clip(ciou,0)  (GR=1)
            const float obj = fmaxf(ciou, 0.0f);
            const unsigned long long packed =
                ((unsigned long long)(unsigned)(r + 1) << 32) |
                (unsigned long long)__float_as_uint(obj);
            atomicMax(&tobj[cell], packed);

            // lcls over 80 classes
            float s = 0.0f;
            #pragma unroll 4
            for (int ch = 0; ch < NCLS; ++ch) {
                const float y = (ch == c) ? 1.0f : 0.0f;
                s += bce_logit(ps[5 + ch], y);
            }
            lc = s;
        }
    }

    // wave reduce -> double atomics (4 per block per accumulator)
    const float wlb = wave_reduce(lb);
    const float wlc = wave_reduce(lc);
    const int   wcn = wave_reduce_i(cnt);
    if ((threadIdx.x & 63) == 0) {
        if (wlb != 0.0f) atomicAdd(&acc[level],     (double)wlb);
        if (wlc != 0.0f) atomicAdd(&acc[3+level],   (double)wlc);
        if (wcn != 0)    atomicAdd(&nv[level], wcn);
    }
}

// Kernel 2: dense obj term — one thread per cell across all 3 levels.
__global__ void obj_kernel(const float* __restrict__ p0,
                           const float* __restrict__ p1,
                           const float* __restrict__ p2,
                           const unsigned long long* __restrict__ tobj_base,
                           double* __restrict__ acc)
{
    const int idx = blockIdx.x * blockDim.x + threadIdx.x;
    float val = 0.0f;
    if (idx < CTOT) {
        const float* p; int cell; float invn; const unsigned long long* tb;
        if (idx < C0)           { p = p0; cell = idx;          tb = tobj_base;          invn = 1.0f/(float)C0; }
        else if (idx < C0+C1)   { p = p1; cell = idx - C0;     tb = tobj_base + C0;     invn = 1.0f/(float)C1; }
        else                    { p = p2; cell = idx - C0 - C1; tb = tobj_base + C0 + C1; invn = 1.0f/(float)C2; }
        const float x = p[(size_t)cell * 85 + 4];
        const float t = __uint_as_float((unsigned)(tb[cell] & 0xffffffffULL));
        val = bce_logit(x, t) * invn;
    }
    const float w = wave_reduce(val);
    if ((threadIdx.x & 63) == 0) atomicAdd(&acc[6], (double)w);
}

// Kernel 3: finalize.
__global__ void fin_kernel(const double* __restrict__ acc,
                           const int* __restrict__ nv,
                           float* __restrict__ out)
{
    if (threadIdx.x == 0 && blockIdx.x == 0) {
        double lbox = 0.0, lcls = 0.0;
        #pragma unroll
        for (int i = 0; i < 3; ++i) {
            const double n = (double)max(nv[i], 1);
            lbox += acc[i]     / n;
            lcls += acc[3+i]   / (n * (double)NCLS);
        }
        lbox *= 0.05;           // BOX_GAIN
        lcls *= 0.5;            // CLS_GAIN
        const double lobj = acc[6];   // OBJ_GAIN = 1 applied twice = 1
        const double loss = (lbox + lobj + lcls) * (double)BSZ;
        out[0] = (float)loss;
        out[1] = (float)lbox;
        out[2] = (float)lobj;
        out[3] = (float)lcls;
    }
}

extern "C" void kernel_launch(void* const* d_in, const int* in_sizes, int n_in,
                              void* d_out, int out_size, void* d_ws, size_t ws_size,
                              hipStream_t stream)
{
    const float* p0 = (const float*)d_in[0];
    const float* p1 = (const float*)d_in[1];
    const float* p2 = (const float*)d_in[2];
    const float* targets = (const float*)d_in[3];
    const float* anchors = (const float*)d_in[4];

    double* acc = (double*)d_ws;                                   // 8 doubles
    int* nv = (int*)((char*)d_ws + 64);                            // 3 ints
    unsigned long long* tobj = (unsigned long long*)((char*)d_ws + 128);

    const size_t clear_bytes = 128 + (size_t)CTOT * 8ull;          // ~3.23 MB
    hipMemsetAsync(d_ws, 0, clear_bytes, stream);

    dim3 g1(M5 / 256, 3);
    cand_kernel<<<g1, 256, 0, stream>>>(p0, p1, p2, targets, anchors, acc, nv, tobj);

    obj_kernel<<<(CTOT + 255) / 256, 256, 0, stream>>>(p0, p1, p2, tobj, acc);

    fin_kernel<<<1, 64, 0, stream>>>(acc, nv, (float*)d_out);
}

// Round 4
// 183.360 us; speedup vs baseline: 1.4560x; 1.4560x over previous
//
#include <hip/hip_runtime.h>
#include <math.h>

// ---- problem constants ----
#define NCLS 80
#define NANC 3
#define NT   512
#define BSZ  16
#define MM   (NANC*NT)    // 1536
#define M5   (5*MM)       // 7680
#define EPSF 1e-7f

// level cell counts: bs*NA*H*W
#define C0 (16*3*80*80)   // 307200
#define C1 (16*3*40*40)   // 76800
#define C2 (16*3*20*20)   // 19200
#define CTOT (C0+C1+C2)   // 403200

// obj pass geometry
#define OBJ_K 4                                    // cells per thread
#define OBJ_T ((CTOT + OBJ_K - 1) / OBJ_K)         // 100800 threads
#define OBJ_B ((OBJ_T + 255) / 256)                // 394 blocks
#define OBJ_STRIDE (OBJ_B * 256)                   // 100864

__device__ __forceinline__ float softplus_neg_abs(float x) {
    // log1p(exp(-|x|)) — |x|>16 ⇒ true value <1e-7; fast-math error ~1e-7 abs: fine
    return __logf(1.0f + __expf(-fabsf(x)));
}
__device__ __forceinline__ float bce_logit(float x, float t) {
    return fmaxf(x, 0.0f) - x * t + softplus_neg_abs(x);
}
__device__ __forceinline__ float sigmoidf(float x) {
    return 1.0f / (1.0f + __expf(-x));
}
__device__ __forceinline__ float wave_reduce(float v) {
    #pragma unroll
    for (int o = 32; o > 0; o >>= 1) v += __shfl_down(v, o);
    return v;
}
__device__ __forceinline__ int wave_reduce_i(int v) {
    #pragma unroll
    for (int o = 32; o > 0; o >>= 1) v += __shfl_down(v, o);
    return v;
}

// ws layout (IDENTICAL footprint to the R1 kernel that passed — do not extend):
//   [0,64)              : double acc[8]  (0..2 lbox/level, 3..5 lcls/level, 6 lobj)
//   [64,128)            : int nv[3]
//   [128, 128+CTOT*8)   : packed tobj (u64: hi=cand idx+1, lo=f32 obj bits)

// Kernel 1: per-candidate (5 offsets x NA x NT per level).
__global__ __launch_bounds__(256) void cand_kernel(
        const float* __restrict__ p0,
        const float* __restrict__ p1,
        const float* __restrict__ p2,
        const float* __restrict__ targets,
        const float* __restrict__ anchors,
        double* __restrict__ acc,
        int* __restrict__ nv,
        unsigned long long* __restrict__ tobj_base)
{
    const int level = blockIdx.y;
    const int r = blockIdx.x * blockDim.x + threadIdx.x;   // 0..M5-1

    const float* p; int W, H; unsigned long long* tobj;
    if (level == 0)      { p = p0; W = 80; H = 80; tobj = tobj_base; }
    else if (level == 1) { p = p1; W = 40; H = 40; tobj = tobj_base + C0; }
    else                 { p = p2; W = 20; H = 20; tobj = tobj_base + C0 + C1; }

    float lb = 0.0f, lc = 0.0f;
    int cnt = 0;

    if (r < M5) {
        const int off_idx = r / MM;
        const int m  = r - off_idx * MM;
        const int a  = m / NT;
        const int ti = m - a * NT;

        const float img = targets[ti*6 + 0];
        const float cls = targets[ti*6 + 1];
        const float gx  = targets[ti*6 + 2] * (float)W;
        const float gy  = targets[ti*6 + 3] * (float)H;
        const float gw  = targets[ti*6 + 4] * (float)W;
        const float gh  = targets[ti*6 + 5] * (float)H;

        const float aw = anchors[level*6 + a*2 + 0];
        const float ah = anchors[level*6 + a*2 + 1];

        // anchor ratio filter
        const float rw = gw / aw, rh = gh / ah;
        const float mr = fmaxf(fmaxf(rw, 1.0f/rw), fmaxf(rh, 1.0f/rh));
        const bool m0 = mr < 4.0f;

        // offset selection (YOLOv5 build_targets)
        const float fx  = gx - truncf(gx);
        const float fy  = gy - truncf(gy);
        const float gix = (float)W - gx;
        const float giy = (float)H - gy;
        const float fix_ = gix - truncf(gix);
        const float fiy  = giy - truncf(giy);

        bool sel; float ox = 0.0f, oy = 0.0f;
        switch (off_idx) {
            case 0: sel = true; break;
            case 1: sel = (fx   < 0.5f) && (gx  > 1.0f); ox =  0.5f; break;
            case 2: sel = (fy   < 0.5f) && (gy  > 1.0f); oy =  0.5f; break;
            case 3: sel = (fix_ < 0.5f) && (gix > 1.0f); ox = -0.5f; break;
            default:sel = (fiy  < 0.5f) && (giy > 1.0f); oy = -0.5f; break;
        }

        if (sel && m0) {
            const int b = (int)img;
            const int c = (int)cls;
            int gi = (int)truncf(gx - ox);
            int gj = (int)truncf(gy - oy);
            gi = min(max(gi, 0), W - 1);
            gj = min(max(gj, 0), H - 1);

            const float tbx = gx - (float)gi;
            const float tby = gy - (float)gj;

            const int cell = ((b*NANC + a)*H + gj)*W + gi;
            const float* ps = p + (size_t)cell * 85;

            const float s0 = ps[0], s1 = ps[1], s2 = ps[2], s3 = ps[3];
            const float pxc = sigmoidf(s0)*2.0f - 0.5f;
            const float pyc = sigmoidf(s1)*2.0f - 0.5f;
            float t2 = sigmoidf(s2)*2.0f; const float pw = t2*t2*aw;
            float t3 = sigmoidf(s3)*2.0f; const float ph = t3*t3*ah;

            // CIoU (exact EPS placement per reference)
            const float b1x1 = pxc - pw*0.5f, b1x2 = pxc + pw*0.5f;
            const float b1y1 = pyc - ph*0.5f, b1y2 = pyc + ph*0.5f;
            const float b2x1 = tbx - gw*0.5f, b2x2 = tbx + gw*0.5f;
            const float b2y1 = tby - gh*0.5f, b2y2 = tby + gh*0.5f;

            const float iw = fmaxf(fminf(b1x2, b2x2) - fmaxf(b1x1, b2x1), 0.0f);
            const float ih = fmaxf(fminf(b1y2, b2y2) - fmaxf(b1y1, b2y1), 0.0f);
            const float inter = iw * ih;

            const float w1 = b1x2 - b1x1, h1 = b1y2 - b1y1 + EPSF;
            const float w2 = b2x2 - b2x1, h2 = b2y2 - b2y1 + EPSF;
            const float uni = w1*h1 + w2*h2 - inter + EPSF;
            const float iou = inter / uni;

            const float cw = fmaxf(b1x2, b2x2) - fminf(b1x1, b2x1);
            const float chh = fmaxf(b1y2, b2y2) - fminf(b1y1, b2y1);
            const float c2 = cw*cw + chh*chh + EPSF;
            const float dx = b2x1 + b2x2 - b1x1 - b1x2;
            const float dy = b2y1 + b2y2 - b1y1 - b1y2;
            const float rho2 = (dx*dx + dy*dy) * 0.25f;

            const float dat = atanf(w2/h2) - atanf(w1/h1);
            const float v = (4.0f / (float)(M_PI*M_PI)) * dat * dat;
            const float alpha = v / (v - iou + (1.0f + EPSF));
            const float ciou = iou - (rho2/c2 + v*alpha);

            lb = 1.0f - ciou;
            cnt = 1;

            // obj_val = clip(ciou,0)  (GR=1)
            const float obj = fmaxf(ciou, 0.0f);
            const unsigned long long packed =
                ((unsigned long long)(unsigned)(r + 1) << 32) |
                (unsigned long long)__float_as_uint(obj);
            atomicMax(&tobj[cell], packed);

            // lcls: sum over one-hot bce, branch-free:
            //   sum_ch bce(x_ch, [ch==c]) = sum_ch (max(x,0)+softplus(-|x|)) - x_c
            const float* ps5 = ps + 5;
            float s = 0.0f;
            #pragma unroll 8
            for (int ch = 0; ch < NCLS; ++ch) {
                const float x = ps5[ch];
                s += fmaxf(x, 0.0f) + softplus_neg_abs(x);
            }
            lc = s - ps5[c];
        }
    }

    const float wlb = wave_reduce(lb);
    const float wlc = wave_reduce(lc);
    const int   wcn = wave_reduce_i(cnt);
    if ((threadIdx.x & 63) == 0) {
        if (wlb != 0.0f) atomicAdd(&acc[level],   (double)wlb);
        if (wlc != 0.0f) atomicAdd(&acc[3+level], (double)wlc);
        if (wcn != 0)    atomicAdd(&nv[level], wcn);
    }
}

// Kernel 2: dense obj term — OBJ_K cells/thread; one double atomic per block.
__global__ __launch_bounds__(256) void obj_kernel(
        const float* __restrict__ p0,
        const float* __restrict__ p1,
        const float* __restrict__ p2,
        const unsigned long long* __restrict__ tobj_base,
        double* __restrict__ acc)
{
    const int tid = blockIdx.x * 256 + threadIdx.x;

    float xs[OBJ_K];
    float ts[OBJ_K];
    float iv[OBJ_K];
    bool  ok[OBJ_K];

    #pragma unroll
    for (int k = 0; k < OBJ_K; ++k) {
        const int idx = tid + k * OBJ_STRIDE;
        ok[k] = idx < CTOT;
        xs[k] = 0.0f; ts[k] = 0.0f; iv[k] = 0.0f;
        if (ok[k]) {
            const float* p; int cell; float invn;
            if (idx < C0)         { p = p0; cell = idx;           invn = 1.0f/(float)C0; }
            else if (idx < C0+C1) { p = p1; cell = idx - C0;      invn = 1.0f/(float)C1; }
            else                  { p = p2; cell = idx - C0 - C1; invn = 1.0f/(float)C2; }
            xs[k] = p[(size_t)cell * 85 + 4];
            ts[k] = __uint_as_float((unsigned)(tobj_base[idx] & 0xffffffffULL));
            iv[k] = invn;
        }
    }

    float val = 0.0f;
    #pragma unroll
    for (int k = 0; k < OBJ_K; ++k)
        if (ok[k]) val += bce_logit(xs[k], ts[k]) * iv[k];

    __shared__ float sm[4];
    const float w = wave_reduce(val);
    const int wid = threadIdx.x >> 6;
    if ((threadIdx.x & 63) == 0) sm[wid] = w;
    __syncthreads();
    if (threadIdx.x == 0)
        atomicAdd(&acc[6], (double)(sm[0] + sm[1] + sm[2] + sm[3]));
}

// Kernel 3: finalize.
__global__ __launch_bounds__(64) void fin_kernel(
        const double* __restrict__ acc,
        const int* __restrict__ nv,
        float* __restrict__ out)
{
    if (threadIdx.x == 0 && blockIdx.x == 0) {
        const double lobj = acc[6];
        double lbox = 0.0, lcls = 0.0;
        #pragma unroll
        for (int i = 0; i < 3; ++i) {
            const double n = (double)max(nv[i], 1);
            lbox += acc[i]   / n;
            lcls += acc[3+i] / (n * (double)NCLS);
        }
        lbox *= 0.05;   // BOX_GAIN
        lcls *= 0.5;    // CLS_GAIN
        const double loss = (lbox + lobj + lcls) * (double)BSZ;
        out[0] = (float)loss;
        out[1] = (float)lbox;
        out[2] = (float)lobj;
        out[3] = (float)lcls;
    }
}

extern "C" void kernel_launch(void* const* d_in, const int* in_sizes, int n_in,
                              void* d_out, int out_size, void* d_ws, size_t ws_size,
                              hipStream_t stream)
{
    const float* p0 = (const float*)d_in[0];
    const float* p1 = (const float*)d_in[1];
    const float* p2 = (const float*)d_in[2];
    const float* targets = (const float*)d_in[3];
    const float* anchors = (const float*)d_in[4];

    double* acc = (double*)d_ws;
    int* nv = (int*)((char*)d_ws + 64);
    unsigned long long* tobj = (unsigned long long*)((char*)d_ws + 128);

    // zero acc/nv/tobj — same footprint as the R1 kernel that passed
    hipMemsetAsync(d_ws, 0, 128 + (size_t)CTOT * 8ull, stream);

    dim3 g1(M5 / 256, 3);
    cand_kernel<<<g1, 256, 0, stream>>>(p0, p1, p2, targets, anchors, acc, nv, tobj);

    obj_kernel<<<OBJ_B, 256, 0, stream>>>(p0, p1, p2, tobj, acc);

    fin_kernel<<<1, 64, 0, stream>>>(acc, nv, (float*)d_out);
}